// Round 1
// baseline (192.119 us; speedup 1.0000x reference)
//
#include <hip/hip_runtime.h>
#include <stdint.h>

// Problem constants
#define BB 16
#define CC 512
#define CQK 64
#define NN 1024   // H*W = 32*32

typedef __attribute__((ext_vector_type(8))) short bf16x8;
typedef __attribute__((ext_vector_type(4))) short short4v;
typedef __attribute__((ext_vector_type(4))) float f32x4;

static __device__ __forceinline__ unsigned short f2bf(float f) {
  uint32_t u = __float_as_uint(f);
  u += 0x7FFFu + ((u >> 16) & 1u);
  return (unsigned short)(u >> 16);
}

// ---------------------------------------------------------------------------
// Kernel 1: pack Wq|Wk|Wv -> bf16 Wall[640][512]
// ---------------------------------------------------------------------------
__global__ __launch_bounds__(256) void k_pack_w(
    const float* __restrict__ Wq, const float* __restrict__ Wk,
    const float* __restrict__ Wv, unsigned short* __restrict__ Wall) {
  int idx = blockIdx.x * 256 + threadIdx.x;  // quad index
  int e = idx * 4;
  if (e >= 640 * 512) return;
  int o = e >> 9;        // /512
  int c = e & 511;
  const float* src;
  if (o < 64)        src = Wq + (size_t)o * 512;
  else if (o < 128)  src = Wk + (size_t)(o - 64) * 512;
  else               src = Wv + (size_t)(o - 128) * 512;
  float4 v = *(const float4*)(src + c);
  short4v pk;
  pk[0] = (short)f2bf(v.x); pk[1] = (short)f2bf(v.y);
  pk[2] = (short)f2bf(v.z); pk[3] = (short)f2bf(v.w);
  *(short4v*)(Wall + e) = pk;
}

// ---------------------------------------------------------------------------
// Kernel 2: transpose x[b][c][n] (fp32) -> xT[b][n][c] (bf16)
// grid (N/32, C/32, B), block 256
// ---------------------------------------------------------------------------
__global__ __launch_bounds__(256) void k_transpose_x(
    const float* __restrict__ x, unsigned short* __restrict__ xT) {
  __shared__ float tile[32][33];
  int b = blockIdx.z;
  int c0 = blockIdx.y * 32;
  int n0 = blockIdx.x * 32;
  int t = threadIdx.x;
  int tn = t & 31, tc = t >> 5;  // tc 0..7
  const float* xp = x + ((size_t)b * CC + c0) * NN + n0;
#pragma unroll
  for (int i = 0; i < 4; i++) {
    int c = tc + i * 8;
    tile[c][tn] = xp[(size_t)c * NN + tn];
  }
  __syncthreads();
  unsigned short* xq = xT + ((size_t)b * NN + n0) * CC + c0;
#pragma unroll
  for (int i = 0; i < 4; i++) {
    int n = tc + i * 8;
    xq[(size_t)n * CC + tn] = f2bf(tile[tn][n]);
  }
}

// ---------------------------------------------------------------------------
// Kernel 3: GEMM1  D[o][n] = sum_c Wall[o][c] * xT[b][n][c]  + bias
//   o in [0,640). o<128 -> qkT[b][n][o] (transposed store, bf16)
//                 o>=128 -> vbuf[b][o-128][n] (bf16)
// grid (N/128=8, 640/128=5, B=16), block 256 (4 waves, each 64x64)
// ---------------------------------------------------------------------------
__global__ __launch_bounds__(256) void k_gemm1(
    const unsigned short* __restrict__ Wall, const unsigned short* __restrict__ xT,
    const float* __restrict__ bq, const float* __restrict__ bk,
    const float* __restrict__ bv,
    unsigned short* __restrict__ qkT, unsigned short* __restrict__ vbuf) {
  __shared__ __align__(16) unsigned short ldsA[128 * 32];
  __shared__ __align__(16) unsigned short ldsB[128 * 32];
  int b = blockIdx.z;
  int o0 = blockIdx.y * 128;
  int n0 = blockIdx.x * 128;
  int t = threadIdx.x;
  int w = t >> 6, l = t & 63;
  int wm = w & 1, wn = w >> 1;
  int lr = l & 15, lq = l >> 4;

  f32x4 acc[4][4];
#pragma unroll
  for (int i = 0; i < 4; i++)
#pragma unroll
    for (int j = 0; j < 4; j++) acc[i][j] = (f32x4){0.f, 0.f, 0.f, 0.f};

  const unsigned short* Ab = Wall + (size_t)o0 * CC;
  const unsigned short* Bb = xT + ((size_t)b * NN + n0) * CC;
  int srow = t >> 2;        // 0..63
  int skq = (t & 3) * 8;    // bf16-element offset within 32-wide k tile

  for (int kt = 0; kt < CC; kt += 32) {
#pragma unroll
    for (int p = 0; p < 2; p++) {
      int r = p * 64 + srow;
      *(uint4*)(&ldsA[r * 32 + skq]) = *(const uint4*)(&Ab[(size_t)r * CC + kt + skq]);
      *(uint4*)(&ldsB[r * 32 + skq]) = *(const uint4*)(&Bb[(size_t)r * CC + kt + skq]);
    }
    __syncthreads();
    bf16x8 af[4], bfr[4];
#pragma unroll
    for (int i = 0; i < 4; i++)
      af[i] = *(const bf16x8*)(&ldsA[(wm * 64 + i * 16 + lr) * 32 + lq * 8]);
#pragma unroll
    for (int j = 0; j < 4; j++)
      bfr[j] = *(const bf16x8*)(&ldsB[(wn * 64 + j * 16 + lr) * 32 + lq * 8]);
#pragma unroll
    for (int i = 0; i < 4; i++)
#pragma unroll
      for (int j = 0; j < 4; j++)
        acc[i][j] = __builtin_amdgcn_mfma_f32_16x16x32_bf16(af[i], bfr[j], acc[i][j], 0, 0, 0);
    __syncthreads();
  }

  if (o0 == 0) {
    // q/k section: transposed store qkT[b][n][o], pack 4 consecutive o
#pragma unroll
    for (int i = 0; i < 4; i++) {
      int ob = wm * 64 + i * 16 + lq * 4;
#pragma unroll
      for (int j = 0; j < 4; j++) {
        int n = n0 + wn * 64 + j * 16 + lr;
        short4v pk;
#pragma unroll
        for (int r = 0; r < 4; r++) {
          int o = ob + r;
          float bias = (o < 64) ? bq[o] : bk[o - 64];
          pk[r] = (short)f2bf(acc[i][j][r] + bias);
        }
        *(short4v*)(&qkT[((size_t)b * NN + n) * 128 + ob]) = pk;
      }
    }
  } else {
#pragma unroll
    for (int i = 0; i < 4; i++) {
#pragma unroll
      for (int r = 0; r < 4; r++) {
        int o = o0 + wm * 64 + i * 16 + lq * 4 + r;
        int c = o - 128;
        float bias = bv[c];
#pragma unroll
        for (int j = 0; j < 4; j++) {
          int n = n0 + wn * 64 + j * 16 + lr;
          vbuf[((size_t)b * CC + c) * NN + n] = f2bf(acc[i][j][r] + bias);
        }
      }
    }
  }
}

// ---------------------------------------------------------------------------
// Kernel 4: scores + softmax.  Per block: (b, 16 query rows) x all 1024 keys.
//   S[n][m] = q[n]·k[m] (K=64, frags direct from global qkT), softmax over m,
//   write attn[b][n][m] bf16.
// grid (N/16=64, B=16), block 256
// ---------------------------------------------------------------------------
__global__ __launch_bounds__(256) void k_attn(
    const unsigned short* __restrict__ qkT, unsigned short* __restrict__ attn) {
  __shared__ float S[16 * 1024];  // 64 KB exactly
  int b = blockIdx.y;
  int n0 = blockIdx.x * 16;
  int t = threadIdx.x;
  int w = t >> 6, l = t & 63;
  int lr = l & 15, lq = l >> 4;
  const unsigned short* qk = qkT + (size_t)b * NN * 128;

  bf16x8 aq[2];
#pragma unroll
  for (int ks = 0; ks < 2; ks++)
    aq[ks] = *(const bf16x8*)(&qk[(size_t)(n0 + lr) * 128 + ks * 32 + lq * 8]);

  // wave w handles keys [w*256, (w+1)*256)
  for (int s = 0; s < 16; s++) {
    int m0 = (w * 16 + s) * 16;
    f32x4 a = (f32x4){0.f, 0.f, 0.f, 0.f};
#pragma unroll
    for (int ks = 0; ks < 2; ks++) {
      bf16x8 bk_ = *(const bf16x8*)(&qk[(size_t)(m0 + lr) * 128 + 64 + ks * 32 + lq * 8]);
      a = __builtin_amdgcn_mfma_f32_16x16x32_bf16(aq[ks], bk_, a, 0, 0, 0);
    }
#pragma unroll
    for (int r = 0; r < 4; r++)
      S[(lq * 4 + r) * 1024 + m0 + lr] = a[r];
  }
  __syncthreads();

  // softmax: row = t>>4 (0..15), 16 threads per row (consecutive lanes)
  int row = t >> 4, sl = t & 15;
  float* Sr = &S[row * 1024];
  float mx = -1e30f;
  for (int i = sl; i < 1024; i += 16) mx = fmaxf(mx, Sr[i]);
#pragma unroll
  for (int d = 1; d < 16; d <<= 1) mx = fmaxf(mx, __shfl_xor(mx, d, 64));
  float sum = 0.f;
  for (int i = sl; i < 1024; i += 16) {
    float e = __expf(Sr[i] - mx);
    Sr[i] = e;
    sum += e;
  }
#pragma unroll
  for (int d = 1; d < 16; d <<= 1) sum += __shfl_xor(sum, d, 64);
  float inv = 1.0f / sum;
  unsigned short* ap = attn + ((size_t)b * NN + n0 + row) * NN;
  for (int i = sl; i < 1024; i += 16) ap[i] = f2bf(Sr[i] * inv);
}

// ---------------------------------------------------------------------------
// Kernel 5: GEMM3  attended[c][n] = sum_m vbuf[b][c][m] * attn[b][n][m]
//   epilogue: out = gamma*attended + x   (fp32)
// grid (N/128=8, C/128=4, B=16), block 256
// ---------------------------------------------------------------------------
__global__ __launch_bounds__(256) void k_gemm3(
    const unsigned short* __restrict__ vbuf, const unsigned short* __restrict__ attn,
    const float* __restrict__ x, const float* __restrict__ gamma,
    float* __restrict__ out) {
  __shared__ __align__(16) unsigned short ldsA[128 * 32];
  __shared__ __align__(16) unsigned short ldsB[128 * 32];
  int b = blockIdx.z;
  int c0 = blockIdx.y * 128;
  int n0 = blockIdx.x * 128;
  int t = threadIdx.x;
  int w = t >> 6, l = t & 63;
  int wm = w & 1, wn = w >> 1;
  int lr = l & 15, lq = l >> 4;

  f32x4 acc[4][4];
#pragma unroll
  for (int i = 0; i < 4; i++)
#pragma unroll
    for (int j = 0; j < 4; j++) acc[i][j] = (f32x4){0.f, 0.f, 0.f, 0.f};

  const unsigned short* Ab = vbuf + ((size_t)b * CC + c0) * NN;
  const unsigned short* Bb = attn + ((size_t)b * NN + n0) * NN;
  int srow = t >> 2;
  int skq = (t & 3) * 8;

  for (int kt = 0; kt < NN; kt += 32) {
#pragma unroll
    for (int p = 0; p < 2; p++) {
      int r = p * 64 + srow;
      *(uint4*)(&ldsA[r * 32 + skq]) = *(const uint4*)(&Ab[(size_t)r * NN + kt + skq]);
      *(uint4*)(&ldsB[r * 32 + skq]) = *(const uint4*)(&Bb[(size_t)r * NN + kt + skq]);
    }
    __syncthreads();
    bf16x8 af[4], bfr[4];
#pragma unroll
    for (int i = 0; i < 4; i++)
      af[i] = *(const bf16x8*)(&ldsA[(wm * 64 + i * 16 + lr) * 32 + lq * 8]);
#pragma unroll
    for (int j = 0; j < 4; j++)
      bfr[j] = *(const bf16x8*)(&ldsB[(wn * 64 + j * 16 + lr) * 32 + lq * 8]);
#pragma unroll
    for (int i = 0; i < 4; i++)
#pragma unroll
      for (int j = 0; j < 4; j++)
        acc[i][j] = __builtin_amdgcn_mfma_f32_16x16x32_bf16(af[i], bfr[j], acc[i][j], 0, 0, 0);
    __syncthreads();
  }

  float g = gamma[0];
#pragma unroll
  for (int i = 0; i < 4; i++) {
#pragma unroll
    for (int r = 0; r < 4; r++) {
      int c = c0 + wm * 64 + i * 16 + lq * 4 + r;
#pragma unroll
      for (int j = 0; j < 4; j++) {
        int n = n0 + wn * 64 + j * 16 + lr;
        size_t idx = ((size_t)b * CC + c) * NN + n;
        out[idx] = g * acc[i][j][r] + x[idx];
      }
    }
  }
}

// ---------------------------------------------------------------------------
extern "C" void kernel_launch(void* const* d_in, const int* in_sizes, int n_in,
                              void* d_out, int out_size, void* d_ws, size_t ws_size,
                              hipStream_t stream) {
  (void)in_sizes; (void)n_in; (void)out_size; (void)ws_size;
  const float* x     = (const float*)d_in[0];
  const float* Wq    = (const float*)d_in[1];
  const float* bq    = (const float*)d_in[2];
  const float* Wk    = (const float*)d_in[3];
  const float* bk    = (const float*)d_in[4];
  const float* Wv    = (const float*)d_in[5];
  const float* bv    = (const float*)d_in[6];
  const float* gamma = (const float*)d_in[7];
  float* out = (float*)d_out;

  char* ws = (char*)d_ws;
  // bf16 scratch buffers (all fully rewritten each call)
  unsigned short* Wall = (unsigned short*)(ws);                       // 640*512*2      =   655,360
  unsigned short* xT   = (unsigned short*)(ws + 655360);              // 16*1024*512*2  = 16,777,216
  unsigned short* qkT  = (unsigned short*)(ws + 655360 + 16777216);   // 16*1024*128*2  =  4,194,304
  unsigned short* vbuf = (unsigned short*)(ws + 655360 + 16777216 + 4194304);            // 16,777,216
  unsigned short* attn = (unsigned short*)(ws + 655360 + 16777216 + 4194304 + 16777216); // 33,554,432
  // total ~71.96 MB

  k_pack_w<<<dim3(320), dim3(256), 0, stream>>>(Wq, Wk, Wv, Wall);
  k_transpose_x<<<dim3(NN / 32, CC / 32, BB), dim3(256), 0, stream>>>(x, xT);
  k_gemm1<<<dim3(NN / 128, 640 / 128, BB), dim3(256), 0, stream>>>(Wall, xT, bq, bk, bv, qkT, vbuf);
  k_attn<<<dim3(NN / 16, BB), dim3(256), 0, stream>>>(qkT, attn);
  k_gemm3<<<dim3(NN / 128, CC / 128, BB), dim3(256), 0, stream>>>(vbuf, attn, x, gamma, out);
}

// Round 2
// 180.883 us; speedup vs baseline: 1.0621x; 1.0621x over previous
//
#include <hip/hip_runtime.h>
#include <stdint.h>

// Problem constants
#define BB 16
#define CC 512
#define CQK 64
#define NN 1024   // H*W = 32*32

typedef __attribute__((ext_vector_type(8))) short bf16x8;
typedef __attribute__((ext_vector_type(4))) short short4v;
typedef __attribute__((ext_vector_type(8))) unsigned short ushort8;
typedef __attribute__((ext_vector_type(4))) float f32x4;

static __device__ __forceinline__ unsigned short f2bf(float f) {
  uint32_t u = __float_as_uint(f);
  u += 0x7FFFu + ((u >> 16) & 1u);
  return (unsigned short)(u >> 16);
}

// Async global->LDS, 16B per lane. LDS dest = wave-uniform base + lane*16.
// AS casts via uintptr_t truncation (CK idiom).
static __device__ __forceinline__ void gll16(const unsigned short* g, unsigned short* l) {
  const __attribute__((address_space(1))) unsigned int* gp =
      reinterpret_cast<const __attribute__((address_space(1))) unsigned int*>(
          reinterpret_cast<uintptr_t>(g));
  __attribute__((address_space(3))) unsigned int* lp =
      reinterpret_cast<__attribute__((address_space(3))) unsigned int*>(
          (unsigned int)reinterpret_cast<uintptr_t>(l));
  __builtin_amdgcn_global_load_lds(gp, lp, 16, 0, 0);
}

// ---------------------------------------------------------------------------
// Kernel 1: pack Wq|Wk|Wv -> bf16 Wall[640][512]
// ---------------------------------------------------------------------------
__global__ __launch_bounds__(256) void k_pack_w(
    const float* __restrict__ Wq, const float* __restrict__ Wk,
    const float* __restrict__ Wv, unsigned short* __restrict__ Wall) {
  int idx = blockIdx.x * 256 + threadIdx.x;  // quad index
  int e = idx * 4;
  if (e >= 640 * 512) return;
  int o = e >> 9;        // /512
  int c = e & 511;
  const float* src;
  if (o < 64)        src = Wq + (size_t)o * 512;
  else if (o < 128)  src = Wk + (size_t)(o - 64) * 512;
  else               src = Wv + (size_t)(o - 128) * 512;
  float4 v = *(const float4*)(src + c);
  short4v pk;
  pk[0] = (short)f2bf(v.x); pk[1] = (short)f2bf(v.y);
  pk[2] = (short)f2bf(v.z); pk[3] = (short)f2bf(v.w);
  *(short4v*)(Wall + e) = pk;
}

// ---------------------------------------------------------------------------
// Kernel 2: transpose x[b][c][n] (fp32) -> xT[b][n][c] (bf16)
// grid (N/32, C/32, B), block 256
// ---------------------------------------------------------------------------
__global__ __launch_bounds__(256) void k_transpose_x(
    const float* __restrict__ x, unsigned short* __restrict__ xT) {
  __shared__ float tile[32][33];
  int b = blockIdx.z;
  int c0 = blockIdx.y * 32;
  int n0 = blockIdx.x * 32;
  int t = threadIdx.x;
  int tn = t & 31, tc = t >> 5;  // tc 0..7
  const float* xp = x + ((size_t)b * CC + c0) * NN + n0;
#pragma unroll
  for (int i = 0; i < 4; i++) {
    int c = tc + i * 8;
    tile[c][tn] = xp[(size_t)c * NN + tn];
  }
  __syncthreads();
  // vectorized store: thread t -> row n = t>>3, cols cq*4..cq*4+3
  unsigned short* xq = xT + ((size_t)b * NN + n0) * CC + c0;
  int n = t >> 3;
  int cq = (t & 7) * 4;
  short4v pk;
#pragma unroll
  for (int k = 0; k < 4; k++) pk[k] = (short)f2bf(tile[cq + k][n]);
  *(short4v*)(&xq[(size_t)n * CC + cq]) = pk;
}

// ---------------------------------------------------------------------------
// Kernel 3: GEMM1  D[o][n] = sum_c Wall[o][c] * xT[b][n][c]  + bias
//   o in [0,640). o<128 -> qkT[b][n][o] (transposed store, bf16)
//                 o>=128 -> vbuf[b][o-128][n] (bf16)
// grid (N/128=8, 640/128=5, B=16), block 256 (4 waves, each 64x64)
// ---------------------------------------------------------------------------
__global__ __launch_bounds__(256) void k_gemm1(
    const unsigned short* __restrict__ Wall, const unsigned short* __restrict__ xT,
    const float* __restrict__ bq, const float* __restrict__ bk,
    const float* __restrict__ bv,
    unsigned short* __restrict__ qkT, unsigned short* __restrict__ vbuf) {
  __shared__ __align__(16) unsigned short ldsA[128 * 32];
  __shared__ __align__(16) unsigned short ldsB[128 * 32];
  int b = blockIdx.z;
  int o0 = blockIdx.y * 128;
  int n0 = blockIdx.x * 128;
  int t = threadIdx.x;
  int w = t >> 6, l = t & 63;
  int wm = w & 1, wn = w >> 1;
  int lr = l & 15, lq = l >> 4;

  f32x4 acc[4][4];
#pragma unroll
  for (int i = 0; i < 4; i++)
#pragma unroll
    for (int j = 0; j < 4; j++) acc[i][j] = (f32x4){0.f, 0.f, 0.f, 0.f};

  const unsigned short* Ab = Wall + (size_t)o0 * CC;
  const unsigned short* Bb = xT + ((size_t)b * NN + n0) * CC;
  int srow = t >> 2;        // 0..63
  int skq = (t & 3) * 8;    // bf16-element offset within 32-wide k tile
  int ldsw = (t >> 6) * 512;  // wave-uniform LDS base (ushort units): wave*1024B

  for (int kt = 0; kt < CC; kt += 32) {
#pragma unroll
    for (int p = 0; p < 2; p++) {
      int r = p * 64 + srow;
      gll16(&Ab[(size_t)r * CC + kt + skq], &ldsA[p * 2048 + ldsw]);
      gll16(&Bb[(size_t)r * CC + kt + skq], &ldsB[p * 2048 + ldsw]);
    }
    __syncthreads();
    bf16x8 af[4], bfr[4];
#pragma unroll
    for (int i = 0; i < 4; i++)
      af[i] = *(const bf16x8*)(&ldsA[(wm * 64 + i * 16 + lr) * 32 + lq * 8]);
#pragma unroll
    for (int j = 0; j < 4; j++)
      bfr[j] = *(const bf16x8*)(&ldsB[(wn * 64 + j * 16 + lr) * 32 + lq * 8]);
#pragma unroll
    for (int i = 0; i < 4; i++)
#pragma unroll
      for (int j = 0; j < 4; j++)
        acc[i][j] = __builtin_amdgcn_mfma_f32_16x16x32_bf16(af[i], bfr[j], acc[i][j], 0, 0, 0);
    __syncthreads();
  }

  if (o0 == 0) {
    // q/k section: transposed store qkT[b][n][o], pack 4 consecutive o
#pragma unroll
    for (int i = 0; i < 4; i++) {
      int ob = wm * 64 + i * 16 + lq * 4;
#pragma unroll
      for (int j = 0; j < 4; j++) {
        int n = n0 + wn * 64 + j * 16 + lr;
        short4v pk;
#pragma unroll
        for (int r = 0; r < 4; r++) {
          int o = ob + r;
          float bias = (o < 64) ? bq[o] : bk[o - 64];
          pk[r] = (short)f2bf(acc[i][j][r] + bias);
        }
        *(short4v*)(&qkT[((size_t)b * NN + n) * 128 + ob]) = pk;
      }
    }
  } else {
#pragma unroll
    for (int i = 0; i < 4; i++) {
#pragma unroll
      for (int r = 0; r < 4; r++) {
        int o = o0 + wm * 64 + i * 16 + lq * 4 + r;
        int c = o - 128;
        float bias = bv[c];
#pragma unroll
        for (int j = 0; j < 4; j++) {
          int n = n0 + wn * 64 + j * 16 + lr;
          vbuf[((size_t)b * CC + c) * NN + n] = f2bf(acc[i][j][r] + bias);
        }
      }
    }
  }
}

// ---------------------------------------------------------------------------
// Kernel 4: scores + softmax.  Per block: (b, 16 query rows) x all 1024 keys.
//   Phase 1: S[n][m] = q[n]·k[m] (K=64, frags from global qkT) -> LDS fp32.
//   Phase 2: wave w owns rows 4w..4w+3; one LDS read pass into regs,
//            full-wave shuffle max/sum, coalesced 16B bf16 stores.
// grid (N/16=64, B=16), block 256
// ---------------------------------------------------------------------------
__global__ __launch_bounds__(256) void k_attn(
    const unsigned short* __restrict__ qkT, unsigned short* __restrict__ attn) {
  __shared__ float S[16 * 1024];  // 64 KB exactly
  int b = blockIdx.y;
  int n0 = blockIdx.x * 16;
  int t = threadIdx.x;
  int w = t >> 6, l = t & 63;
  int lr = l & 15, lq = l >> 4;
  const unsigned short* qk = qkT + (size_t)b * NN * 128;

  bf16x8 aq[2];
#pragma unroll
  for (int ks = 0; ks < 2; ks++)
    aq[ks] = *(const bf16x8*)(&qk[(size_t)(n0 + lr) * 128 + ks * 32 + lq * 8]);

  // wave w handles keys [w*256, (w+1)*256)
  for (int s = 0; s < 16; s++) {
    int m0 = w * 256 + s * 16;
    f32x4 a = (f32x4){0.f, 0.f, 0.f, 0.f};
#pragma unroll
    for (int ks = 0; ks < 2; ks++) {
      bf16x8 bk_ = *(const bf16x8*)(&qk[(size_t)(m0 + lr) * 128 + 64 + ks * 32 + lq * 8]);
      a = __builtin_amdgcn_mfma_f32_16x16x32_bf16(aq[ks], bk_, a, 0, 0, 0);
    }
#pragma unroll
    for (int r = 0; r < 4; r++)
      S[(lq * 4 + r) * 1024 + m0 + lr] = a[r];
  }
  __syncthreads();

  // Phase 2: wave w -> rows 4w..4w+3. Lane l owns 16 contiguous columns.
#pragma unroll
  for (int rr = 0; rr < 4; rr++) {
    int row = w * 4 + rr;
    const float* Sr = &S[row * 1024];
    f32x4 v[4];
#pragma unroll
    for (int i = 0; i < 4; i++) v[i] = *(const f32x4*)(&Sr[l * 16 + i * 4]);
    float mx = -1e30f;
#pragma unroll
    for (int i = 0; i < 4; i++)
#pragma unroll
      for (int j = 0; j < 4; j++) mx = fmaxf(mx, v[i][j]);
#pragma unroll
    for (int d = 1; d < 64; d <<= 1) mx = fmaxf(mx, __shfl_xor(mx, d, 64));
    float sum = 0.f;
#pragma unroll
    for (int i = 0; i < 4; i++)
#pragma unroll
      for (int j = 0; j < 4; j++) {
        float e = __expf(v[i][j] - mx);
        v[i][j] = e;
        sum += e;
      }
#pragma unroll
    for (int d = 1; d < 64; d <<= 1) sum += __shfl_xor(sum, d, 64);
    float inv = 1.0f / sum;
    ushort8 p0, p1;
#pragma unroll
    for (int j = 0; j < 4; j++) {
      p0[j]     = f2bf(v[0][j] * inv);
      p0[4 + j] = f2bf(v[1][j] * inv);
      p1[j]     = f2bf(v[2][j] * inv);
      p1[4 + j] = f2bf(v[3][j] * inv);
    }
    unsigned short* ap = attn + ((size_t)b * NN + n0 + row) * NN + l * 16;
    *(ushort8*)(ap) = p0;
    *(ushort8*)(ap + 8) = p1;
  }
}

// ---------------------------------------------------------------------------
// Kernel 5: GEMM3  attended[c][n] = sum_m vbuf[b][c][m] * attn[b][n][m]
//   epilogue: out = gamma*attended + x   (fp32)
// grid (N/128=8, C/128=4, B=16), block 256
// ---------------------------------------------------------------------------
__global__ __launch_bounds__(256) void k_gemm3(
    const unsigned short* __restrict__ vbuf, const unsigned short* __restrict__ attn,
    const float* __restrict__ x, const float* __restrict__ gamma,
    float* __restrict__ out) {
  __shared__ __align__(16) unsigned short ldsA[128 * 32];
  __shared__ __align__(16) unsigned short ldsB[128 * 32];
  int b = blockIdx.z;
  int c0 = blockIdx.y * 128;
  int n0 = blockIdx.x * 128;
  int t = threadIdx.x;
  int w = t >> 6, l = t & 63;
  int wm = w & 1, wn = w >> 1;
  int lr = l & 15, lq = l >> 4;

  f32x4 acc[4][4];
#pragma unroll
  for (int i = 0; i < 4; i++)
#pragma unroll
    for (int j = 0; j < 4; j++) acc[i][j] = (f32x4){0.f, 0.f, 0.f, 0.f};

  const unsigned short* Ab = vbuf + ((size_t)b * CC + c0) * NN;
  const unsigned short* Bb = attn + ((size_t)b * NN + n0) * NN;
  int srow = t >> 2;
  int skq = (t & 3) * 8;
  int ldsw = (t >> 6) * 512;  // wave-uniform LDS base (ushort units)

  for (int kt = 0; kt < NN; kt += 32) {
#pragma unroll
    for (int p = 0; p < 2; p++) {
      int r = p * 64 + srow;
      gll16(&Ab[(size_t)r * NN + kt + skq], &ldsA[p * 2048 + ldsw]);
      gll16(&Bb[(size_t)r * NN + kt + skq], &ldsB[p * 2048 + ldsw]);
    }
    __syncthreads();
    bf16x8 af[4], bfr[4];
#pragma unroll
    for (int i = 0; i < 4; i++)
      af[i] = *(const bf16x8*)(&ldsA[(wm * 64 + i * 16 + lr) * 32 + lq * 8]);
#pragma unroll
    for (int j = 0; j < 4; j++)
      bfr[j] = *(const bf16x8*)(&ldsB[(wn * 64 + j * 16 + lr) * 32 + lq * 8]);
#pragma unroll
    for (int i = 0; i < 4; i++)
#pragma unroll
      for (int j = 0; j < 4; j++)
        acc[i][j] = __builtin_amdgcn_mfma_f32_16x16x32_bf16(af[i], bfr[j], acc[i][j], 0, 0, 0);
    __syncthreads();
  }

  float g = gamma[0];
#pragma unroll
  for (int i = 0; i < 4; i++) {
#pragma unroll
    for (int r = 0; r < 4; r++) {
      int c = c0 + wm * 64 + i * 16 + lq * 4 + r;
#pragma unroll
      for (int j = 0; j < 4; j++) {
        int n = n0 + wn * 64 + j * 16 + lr;
        size_t idx = ((size_t)b * CC + c) * NN + n;
        out[idx] = g * acc[i][j][r] + x[idx];
      }
    }
  }
}

// ---------------------------------------------------------------------------
extern "C" void kernel_launch(void* const* d_in, const int* in_sizes, int n_in,
                              void* d_out, int out_size, void* d_ws, size_t ws_size,
                              hipStream_t stream) {
  (void)in_sizes; (void)n_in; (void)out_size; (void)ws_size;
  const float* x     = (const float*)d_in[0];
  const float* Wq    = (const float*)d_in[1];
  const float* bq    = (const float*)d_in[2];
  const float* Wk    = (const float*)d_in[3];
  const float* bk    = (const float*)d_in[4];
  const float* Wv    = (const float*)d_in[5];
  const float* bv    = (const float*)d_in[6];
  const float* gamma = (const float*)d_in[7];
  float* out = (float*)d_out;

  char* ws = (char*)d_ws;
  // bf16 scratch buffers (all fully rewritten each call)
  unsigned short* Wall = (unsigned short*)(ws);                       // 640*512*2      =   655,360
  unsigned short* xT   = (unsigned short*)(ws + 655360);              // 16*1024*512*2  = 16,777,216
  unsigned short* qkT  = (unsigned short*)(ws + 655360 + 16777216);   // 16*1024*128*2  =  4,194,304
  unsigned short* vbuf = (unsigned short*)(ws + 655360 + 16777216 + 4194304);            // 16,777,216
  unsigned short* attn = (unsigned short*)(ws + 655360 + 16777216 + 4194304 + 16777216); // 33,554,432
  // total ~71.96 MB

  k_pack_w<<<dim3(320), dim3(256), 0, stream>>>(Wq, Wk, Wv, Wall);
  k_transpose_x<<<dim3(NN / 32, CC / 32, BB), dim3(256), 0, stream>>>(x, xT);
  k_gemm1<<<dim3(NN / 128, 640 / 128, BB), dim3(256), 0, stream>>>(Wall, xT, bq, bk, bv, qkT, vbuf);
  k_attn<<<dim3(NN / 16, BB), dim3(256), 0, stream>>>(qkT, attn);
  k_gemm3<<<dim3(NN / 128, CC / 128, BB), dim3(256), 0, stream>>>(vbuf, attn, x, gamma, out);
}